// Round 12
// baseline (804.406 us; speedup 1.0000x reference)
//
#include <hip/hip_runtime.h>
#include <stdint.h>

#define H 256
#define NATOMS 100000
#define MB 32
#define NBLK (NATOMS / MB)   // 3125

typedef float floatx4 __attribute__((ext_vector_type(4)));
typedef short short8 __attribute__((ext_vector_type(8)));
typedef short short4v __attribute__((ext_vector_type(4)));

// lgkm-only barrier: global prefetches stay in flight across it.
#define BAR() do { asm volatile("s_waitcnt lgkmcnt(0)\n\ts_barrier" ::: "memory"); __builtin_amdgcn_sched_barrier(0); } while (0)

__device__ __forceinline__ unsigned short f2bf(float x) {
    union { float f; uint32_t u; } c; c.f = x;
    return (unsigned short)((c.u + 0x7FFFu + ((c.u >> 16) & 1u)) >> 16);
}
__device__ __forceinline__ float bf2f(unsigned short h) {
    union { uint32_t u; float f; } c; c.u = ((uint32_t)h) << 16; return c.f;
}
__device__ __forceinline__ uint32_t pk2(float lo, float hi) {
    return (uint32_t)f2bf(lo) | ((uint32_t)f2bf(hi) << 16);
}
__device__ __forceinline__ float upk(uint32_t u, int hi) {
    union { uint32_t u; float f; } c;
    c.u = hi ? (u & 0xFFFF0000u) : (u << 16);
    return c.f;
}

// ---------------------------------------------------------------------------
// Pack weights (f32 [K][N] row-major) into bf16 MFMA-B-fragment order.
// frag fl = nb*(K/32)+kb; lane l holds W[kb*32+(l>>4)*8+e][nb*16+(l&15)].
// ws layout (bf16 elems): U@0, V@65536, W1@131072, W2@262144 (896KB total).
// ---------------------------------------------------------------------------
__global__ void pack_weights(const float* __restrict__ U_W, const float* __restrict__ V_W,
                             const float* __restrict__ W1, const float* __restrict__ W2,
                             unsigned short* __restrict__ P) {
    int gtid = blockIdx.x * 256 + threadIdx.x;
    int fid = gtid >> 6, l = gtid & 63;
    const float* src; int K, N, fl; unsigned short* dst;
    if (fid < 128)      { src = U_W; K = 256; N = 256; fl = fid;       dst = P; }
    else if (fid < 256) { src = V_W; K = 256; N = 256; fl = fid - 128; dst = P + 65536; }
    else if (fid < 512) { src = W1;  K = 512; N = 256; fl = fid - 256; dst = P + 131072; }
    else                { src = W2;  K = 256; N = 768; fl = fid - 512; dst = P + 262144; }
    int kbc = K >> 5;
    int nb = fl / kbc, kb = fl - nb * kbc;
    int k0 = kb * 32 + ((l >> 4) << 3);
    int n0 = nb * 16 + (l & 15);
    short8 outv;
#pragma unroll
    for (int e = 0; e < 8; e++) outv[e] = (short)f2bf(src[(size_t)(k0 + e) * N + n0]);
    *(short8*)(dst + (size_t)fl * 512 + l * 8) = outv;
}

// ---------------------------------------------------------------------------
// Fused PaiNN mixing (R8 structure, LDS squeezed to 48KB -> 3 blocks/CU).
// Block = 32 atoms, 512 thr (8 waves); three independent barrier domains/CU.
// Wave w owns cols [32w,32w+32) (cf 0..1). A-frags 1KB MFMA-linear w/
// kpos-XOR swizzle; lane read off loff = (l>>4)*256 + ((l15^(l>>4))<<4).
// LDS overlay walk (one 48KB array):
//   [0,48K)  VF: v-frags (g*24+d*8+ks)   [staging -> B2]
//   [0,16K)  s_norm frags (g*8+ks)       [B2 -> p2], then sdelta[a][c] [p3 -> epi]
//   [16,32K) Vv_norm frags (g*8+kn)      [B2 -> p2]
//   [32,48K) hid frags (g*8+ks)          [p2 -> p3]
// In regs: raw s (srp), s_norm (snp), Uv (uvh), dotv, a_vv. v re-read in epi.
// ---------------------------------------------------------------------------
__global__ __launch_bounds__(512, 6) void painn_main(
    const float* __restrict__ s, const float* __restrict__ v,
    const float* __restrict__ gamma, const float* __restrict__ beta,
    const float* __restrict__ b1, const float* __restrict__ b2,
    const unsigned short* __restrict__ P,
    float* __restrict__ s_out, float* __restrict__ v_out) {

    __shared__ unsigned short SH[24576];   // 48KB
    char* LB = (char*)SH;

    const int tid = threadIdx.x;
    const int w = tid >> 6, l = tid & 63;
    const int l15 = l & 15, lhi = l >> 4;
    const int loff = (lhi << 8) | ((l15 ^ lhi) << 4);
    const int atom0 = blockIdx.x * MB;
    const int aLN = tid >> 4, lg = tid & 15;          // 16 lanes per atom
    const int gLN = aLN >> 4, a15LN = aLN & 15;

    // ---- stage v -> v-frags [0,48K) ----
    {
        const floatx4* vsrc = (const floatx4*)(v + (size_t)atom0 * 3 * H);
#pragma unroll
        for (int i = 0; i < 6; i++) {
            int p = i * 512 + tid;
            int a = p / 96, rem = p - a * 96;
            int d = rem >> 5, c8 = rem & 31;
            int q = ((a * 3 + d) << 6) + (c8 << 1);
            floatx4 x0 = vsrc[q], x1 = vsrc[q + 1];
            short8 pk;
#pragma unroll
            for (int j = 0; j < 4; j++) { pk[j] = (short)f2bf(x0[j]); pk[4 + j] = (short)f2bf(x1[j]); }
            int ks = c8 >> 2, kpos = c8 & 3;
            int bo = ((((a >> 4) * 24) + d * 8 + ks) << 10) + (kpos << 8) + (((a & 15) ^ kpos) << 4);
            *(short8*)(LB + bo) = pk;
        }
    }

    // ---- LayerNorm(s): s_norm + raw s kept in REGISTERS (no LDS yet) ----
    short4v srp[4], snp[4];
    {
        const floatx4* srow = (const floatx4*)(s + (size_t)(atom0 + aLN) * H);
        floatx4 vals[4];
        float sum = 0.f, sq = 0.f;
#pragma unroll
        for (int i = 0; i < 4; i++) {
            vals[i] = srow[lg + (i << 4)];
#pragma unroll
            for (int j = 0; j < 4; j++) { sum += vals[i][j]; sq += vals[i][j] * vals[i][j]; }
        }
#pragma unroll
        for (int m = 1; m < 16; m <<= 1) { sum += __shfl_xor(sum, m); sq += __shfl_xor(sq, m); }
        float mu = sum * (1.f / 256.f);
        float var = sq * (1.f / 256.f) - mu * mu;
        float rs = rsqrtf(var + 1e-5f);
#pragma unroll
        for (int i = 0; i < 4; i++) {
            int chunk = lg + (i << 4);
            floatx4 g4 = *(const floatx4*)(gamma + chunk * 4);
            floatx4 be4 = *(const floatx4*)(beta + chunk * 4);
            short4v pk, pr;
#pragma unroll
            for (int j = 0; j < 4; j++) {
                pk[j] = (short)f2bf((vals[i][j] - mu) * rs * g4[j] + be4[j]);
                pr[j] = (short)f2bf(vals[i][j]);
            }
            snp[i] = pk;
            srp[i] = pr;
        }
    }

    // ---- p1 B prefetch (cf=0, slot0) before barrier ----
    const short8* PU = (const short8*)P;
    const short8* PV = (const short8*)(P + 65536);
    short8 bU[2], bV[2];
    bU[0] = PU[(size_t)((w * 2) * 8) * 64 + l];
    bV[0] = PV[(size_t)((w * 2) * 8) * 64 + l];

    BAR();  // B1: v-frags visible

    // ---- phase 1: Uv & Vv, per-cf passes (keeps VGPR low) ----
    float dotv[2][2][4];
    uint32_t uvh[2][3][2][2];   // [cf][d][g][pair] packed bf16
    uint32_t nvp[2][2][2];      // [cf][g][pair]   packed bf16
#pragma unroll
    for (int cf = 0; cf < 2; cf++) {
        int nb = w * 2 + cf;
        if (cf == 1) {
            bU[0] = PU[(size_t)(nb * 8) * 64 + l];
            bV[0] = PV[(size_t)(nb * 8) * 64 + l];
        }
        floatx4 accU[3][2], accV[3][2];
#pragma unroll
        for (int d = 0; d < 3; d++)
#pragma unroll
            for (int g = 0; g < 2; g++) { accU[d][g] = (floatx4)0.f; accV[d][g] = (floatx4)0.f; }
#pragma unroll
        for (int ks = 0; ks < 8; ks++) {
            int cur = ks & 1, nxt = cur ^ 1;
            if (ks < 7) {
                bU[nxt] = PU[(size_t)(nb * 8 + ks + 1) * 64 + l];
                bV[nxt] = PV[(size_t)(nb * 8 + ks + 1) * 64 + l];
            }
#pragma unroll
            for (int g = 0; g < 2; g++) {
                short8 af0 = *(const short8*)(LB + ((g * 24 + 0 * 8 + ks) << 10) + loff);
                short8 af1 = *(const short8*)(LB + ((g * 24 + 1 * 8 + ks) << 10) + loff);
                short8 af2 = *(const short8*)(LB + ((g * 24 + 2 * 8 + ks) << 10) + loff);
                __builtin_amdgcn_s_setprio(1);
                accU[0][g] = __builtin_amdgcn_mfma_f32_16x16x32_bf16(af0, bU[cur], accU[0][g], 0, 0, 0);
                accV[0][g] = __builtin_amdgcn_mfma_f32_16x16x32_bf16(af0, bV[cur], accV[0][g], 0, 0, 0);
                accU[1][g] = __builtin_amdgcn_mfma_f32_16x16x32_bf16(af1, bU[cur], accU[1][g], 0, 0, 0);
                accV[1][g] = __builtin_amdgcn_mfma_f32_16x16x32_bf16(af1, bV[cur], accV[1][g], 0, 0, 0);
                accU[2][g] = __builtin_amdgcn_mfma_f32_16x16x32_bf16(af2, bU[cur], accU[2][g], 0, 0, 0);
                accV[2][g] = __builtin_amdgcn_mfma_f32_16x16x32_bf16(af2, bV[cur], accV[2][g], 0, 0, 0);
                __builtin_amdgcn_s_setprio(0);
            }
        }
        // fold: dot_uv, ||Vv||, pack Uv -> bf16
#pragma unroll
        for (int g = 0; g < 2; g++) {
            float nv[4];
#pragma unroll
            for (int j = 0; j < 4; j++) {
                dotv[cf][g][j] = accU[0][g][j] * accV[0][g][j] + accU[1][g][j] * accV[1][g][j]
                               + accU[2][g][j] * accV[2][g][j];
                nv[j] = sqrtf(accV[0][g][j] * accV[0][g][j] + accV[1][g][j] * accV[1][g][j]
                            + accV[2][g][j] * accV[2][g][j] + 1e-8f);
            }
            nvp[cf][g][0] = pk2(nv[0], nv[1]);
            nvp[cf][g][1] = pk2(nv[2], nv[3]);
#pragma unroll
            for (int d = 0; d < 3; d++) {
                uvh[cf][d][g][0] = pk2(accU[d][g][0], accU[d][g][1]);
                uvh[cf][d][g][1] = pk2(accU[d][g][2], accU[d][g][3]);
            }
        }
    }

    BAR();  // B2: all v-frag reads done -> whole 48KB writable

    // ---- s_norm frags -> [0,16K) (from regs) ----
#pragma unroll
    for (int i = 0; i < 4; i++) {
        int chunk = lg + (i << 4);
        int ks2 = chunk >> 3, kpos = (chunk >> 1) & 3, half = chunk & 1;
        int bo = ((gLN * 8 + ks2) << 10) + (kpos << 8) + ((a15LN ^ kpos) << 4) + half * 8;
        *(short4v*)(LB + bo) = snp[i];
    }

    // ---- Vv_norm -> [16,32K) frags ----
#pragma unroll
    for (int cf = 0; cf < 2; cf++) {
        int kp = (cf << 1) | (l15 >> 3);
        int cb = (l15 & 7) << 1;
#pragma unroll
        for (int g = 0; g < 2; g++)
#pragma unroll
            for (int j = 0; j < 4; j++) {
                int a15 = (lhi << 2) + j;
                unsigned short hbits = (unsigned short)((j & 1) ? (nvp[cf][g][j >> 1] >> 16)
                                                                : (nvp[cf][g][j >> 1] & 0xFFFF));
                int bo = 16384 + ((g * 8 + w) << 10) + (kp << 8) + ((a15 ^ kp) << 4) + cb;
                *(unsigned short*)(LB + bo) = hbits;
            }
    }

    // ---- p2 B prefetch ----
    const short8* PW1 = (const short8*)(P + 131072);
    short8 bw[2];
    bw[0] = PW1[(size_t)((w * 2) * 16) * 64 + l];

    BAR();  // B3: s_norm + Vv_norm frags visible

    // ---- phase 2: hid = silu(ctx_in @ W1 + b1), per-cf passes ----
#pragma unroll
    for (int cf = 0; cf < 2; cf++) {
        int nb = w * 2 + cf;
        if (cf == 1) bw[0] = PW1[(size_t)(nb * 16) * 64 + l];
        floatx4 acc2[2];
        acc2[0] = (floatx4)0.f; acc2[1] = (floatx4)0.f;
#pragma unroll
        for (int ks2 = 0; ks2 < 16; ks2++) {
            int cur = ks2 & 1, nxt = cur ^ 1;
            if (ks2 < 15) bw[nxt] = PW1[(size_t)(nb * 16 + ks2 + 1) * 64 + l];
            short8 af0 = (ks2 < 8)
                ? *(const short8*)(LB + ((0 * 8 + ks2) << 10) + loff)
                : *(const short8*)(LB + 16384 + ((0 * 8 + ks2 - 8) << 10) + loff);
            short8 af1 = (ks2 < 8)
                ? *(const short8*)(LB + ((1 * 8 + ks2) << 10) + loff)
                : *(const short8*)(LB + 16384 + ((1 * 8 + ks2 - 8) << 10) + loff);
            __builtin_amdgcn_s_setprio(1);
            acc2[0] = __builtin_amdgcn_mfma_f32_16x16x32_bf16(af0, bw[cur], acc2[0], 0, 0, 0);
            acc2[1] = __builtin_amdgcn_mfma_f32_16x16x32_bf16(af1, bw[cur], acc2[1], 0, 0, 0);
            __builtin_amdgcn_s_setprio(0);
        }
        // hid -> [32,48K) frags (region dead since B2; readers gated by B4)
        int c = (w << 5) + (cf << 4) + l15;
        float bb = b1[c];
        int kp = (cf << 1) | (l15 >> 3);
        int cb = (l15 & 7) << 1;
#pragma unroll
        for (int g = 0; g < 2; g++)
#pragma unroll
            for (int j = 0; j < 4; j++) {
                int a15 = (lhi << 2) + j;
                float x = acc2[g][j] + bb;
                float hh = x / (1.f + __expf(-x));
                int bo = 32768 + ((g * 8 + w) << 10) + (kp << 8) + ((a15 ^ kp) << 4) + cb;
                *(unsigned short*)(LB + bo) = f2bf(hh);
            }
    }

    // ---- p3 B prefetch (first pass = sv segment, sg=1) ----
    const short8* PW2 = (const short8*)(P + 262144);
    short8 b2w[2][2];
    b2w[0][0] = PW2[(size_t)((16 + w * 2 + 0) * 8) * 64 + l];
    b2w[0][1] = PW2[(size_t)((16 + w * 2 + 1) * 8) * 64 + l];

    BAR();  // B4: hid visible; s_norm/Vv_norm dead

    // ---- phase 3: per-segment passes sv -> ss -> vv ----
    float svd[2][2][4];   // sv*dot -> sdelta -> a_vv (reused)
    {   // sv (sg=1)
        floatx4 acc[2][2];
#pragma unroll
        for (int g = 0; g < 2; g++) { acc[g][0] = (floatx4)0.f; acc[g][1] = (floatx4)0.f; }
#pragma unroll
        for (int ks3 = 0; ks3 < 8; ks3++) {
            int cur = ks3 & 1, nxt = cur ^ 1;
            if (ks3 < 7) {
                b2w[nxt][0] = PW2[(size_t)((16 + w * 2 + 0) * 8 + ks3 + 1) * 64 + l];
                b2w[nxt][1] = PW2[(size_t)((16 + w * 2 + 1) * 8 + ks3 + 1) * 64 + l];
            } else {
                b2w[nxt][0] = PW2[(size_t)((0 + w * 2 + 0) * 8) * 64 + l];
                b2w[nxt][1] = PW2[(size_t)((0 + w * 2 + 1) * 8) * 64 + l];
            }
            short8 af0 = *(const short8*)(LB + 32768 + ((0 * 8 + ks3) << 10) + loff);
            short8 af1 = *(const short8*)(LB + 32768 + ((1 * 8 + ks3) << 10) + loff);
            __builtin_amdgcn_s_setprio(1);
            acc[0][0] = __builtin_amdgcn_mfma_f32_16x16x32_bf16(af0, b2w[cur][0], acc[0][0], 0, 0, 0);
            acc[0][1] = __builtin_amdgcn_mfma_f32_16x16x32_bf16(af0, b2w[cur][1], acc[0][1], 0, 0, 0);
            acc[1][0] = __builtin_amdgcn_mfma_f32_16x16x32_bf16(af1, b2w[cur][0], acc[1][0], 0, 0, 0);
            acc[1][1] = __builtin_amdgcn_mfma_f32_16x16x32_bf16(af1, b2w[cur][1], acc[1][1], 0, 0, 0);
            __builtin_amdgcn_s_setprio(0);
        }
#pragma unroll
        for (int cf = 0; cf < 2; cf++) {
            float bsv = b2[256 + (w << 5) + (cf << 4) + l15];
#pragma unroll
            for (int g = 0; g < 2; g++)
#pragma unroll
                for (int j = 0; j < 4; j++)
                    svd[cf][g][j] = (acc[g][cf][j] + bsv) * dotv[cf][g][j];
        }
    }
    {   // ss (sg=0)
        floatx4 acc[2][2];
#pragma unroll
        for (int g = 0; g < 2; g++) { acc[g][0] = (floatx4)0.f; acc[g][1] = (floatx4)0.f; }
#pragma unroll
        for (int ks3 = 0; ks3 < 8; ks3++) {
            int cur = ks3 & 1, nxt = cur ^ 1;
            if (ks3 < 7) {
                b2w[nxt][0] = PW2[(size_t)((w * 2 + 0) * 8 + ks3 + 1) * 64 + l];
                b2w[nxt][1] = PW2[(size_t)((w * 2 + 1) * 8 + ks3 + 1) * 64 + l];
            } else {
                b2w[nxt][0] = PW2[(size_t)((32 + w * 2 + 0) * 8) * 64 + l];
                b2w[nxt][1] = PW2[(size_t)((32 + w * 2 + 1) * 8) * 64 + l];
            }
            short8 af0 = *(const short8*)(LB + 32768 + ((0 * 8 + ks3) << 10) + loff);
            short8 af1 = *(const short8*)(LB + 32768 + ((1 * 8 + ks3) << 10) + loff);
            __builtin_amdgcn_s_setprio(1);
            acc[0][0] = __builtin_amdgcn_mfma_f32_16x16x32_bf16(af0, b2w[cur][0], acc[0][0], 0, 0, 0);
            acc[0][1] = __builtin_amdgcn_mfma_f32_16x16x32_bf16(af0, b2w[cur][1], acc[0][1], 0, 0, 0);
            acc[1][0] = __builtin_amdgcn_mfma_f32_16x16x32_bf16(af1, b2w[cur][0], acc[1][0], 0, 0, 0);
            acc[1][1] = __builtin_amdgcn_mfma_f32_16x16x32_bf16(af1, b2w[cur][1], acc[1][1], 0, 0, 0);
            __builtin_amdgcn_s_setprio(0);
        }
        // sdelta = (ss+bss) + sv*dot -> [0,16K) [a][c] (s_norm dead since B4)
#pragma unroll
        for (int cf = 0; cf < 2; cf++) {
            int c = (w << 5) + (cf << 4) + l15;
            float bss = b2[c];
#pragma unroll
            for (int g = 0; g < 2; g++)
#pragma unroll
                for (int j = 0; j < 4; j++) {
                    int a = (g << 4) + (lhi << 2) + j;
                    float sd = (acc[g][cf][j] + bss) + svd[cf][g][j];
                    int bo = ((a << 9) + (c << 1)) ^ ((a & 7) << 4);
                    *(unsigned short*)(LB + bo) = f2bf(sd);
                }
        }
    }
    {   // vv (sg=2) -> a_vv kept in regs (svd reused)
        floatx4 acc[2][2];
#pragma unroll
        for (int g = 0; g < 2; g++) { acc[g][0] = (floatx4)0.f; acc[g][1] = (floatx4)0.f; }
#pragma unroll
        for (int ks3 = 0; ks3 < 8; ks3++) {
            int cur = ks3 & 1, nxt = cur ^ 1;
            if (ks3 < 7) {
                b2w[nxt][0] = PW2[(size_t)((32 + w * 2 + 0) * 8 + ks3 + 1) * 64 + l];
                b2w[nxt][1] = PW2[(size_t)((32 + w * 2 + 1) * 8 + ks3 + 1) * 64 + l];
            }
            short8 af0 = *(const short8*)(LB + 32768 + ((0 * 8 + ks3) << 10) + loff);
            short8 af1 = *(const short8*)(LB + 32768 + ((1 * 8 + ks3) << 10) + loff);
            __builtin_amdgcn_s_setprio(1);
            acc[0][0] = __builtin_amdgcn_mfma_f32_16x16x32_bf16(af0, b2w[cur][0], acc[0][0], 0, 0, 0);
            acc[0][1] = __builtin_amdgcn_mfma_f32_16x16x32_bf16(af0, b2w[cur][1], acc[0][1], 0, 0, 0);
            acc[1][0] = __builtin_amdgcn_mfma_f32_16x16x32_bf16(af1, b2w[cur][0], acc[1][0], 0, 0, 0);
            acc[1][1] = __builtin_amdgcn_mfma_f32_16x16x32_bf16(af1, b2w[cur][1], acc[1][1], 0, 0, 0);
            __builtin_amdgcn_s_setprio(0);
        }
#pragma unroll
        for (int cf = 0; cf < 2; cf++) {
            float bvv = b2[512 + (w << 5) + (cf << 4) + l15];
#pragma unroll
            for (int g = 0; g < 2; g++)
#pragma unroll
                for (int j = 0; j < 4; j++)
                    svd[cf][g][j] = acc[g][cf][j] + bvv;
        }
    }

    BAR();  // B5: sdelta visible

    // ---- epilogue: s_out (LN map; raw s from regs; coalesced) ----
    {
        size_t gb = (size_t)(atom0 + aLN) * H;
        int xo = (aLN & 7) << 4;
#pragma unroll
        for (int i = 0; i < 4; i++) {
            int chunk = lg + (i << 4);
            short4v sd4 = *(const short4v*)(LB + (((aLN << 9) + (chunk << 3)) ^ xo));
            floatx4 o;
#pragma unroll
            for (int j = 0; j < 4; j++) o[j] = bf2f((unsigned short)srp[i][j]) + bf2f((unsigned short)sd4[j]);
            *(floatx4*)(s_out + gb + chunk * 4) = o;
        }
    }

    // ---- epilogue: v_out = v + a_vv * Uv (v re-read, L2-warm) ----
#pragma unroll
    for (int cf = 0; cf < 2; cf++) {
        int c = (w << 5) + (cf << 4) + l15;
#pragma unroll
        for (int g = 0; g < 2; g++)
#pragma unroll
            for (int j = 0; j < 4; j++) {
                int a = (g << 4) + (lhi << 2) + j;
                size_t base = (size_t)(atom0 + a) * 3 * H + c;
                float av = svd[cf][g][j];
#pragma unroll
                for (int d = 0; d < 3; d++) {
                    float uv = upk(uvh[cf][d][g][j >> 1], j & 1);
                    size_t vi = base + (size_t)d * H;
                    v_out[vi] = v[vi] + av * uv;
                }
            }
    }
}

extern "C" void kernel_launch(void* const* d_in, const int* in_sizes, int n_in,
                              void* d_out, int out_size, void* d_ws, size_t ws_size,
                              hipStream_t stream) {
    const float* s     = (const float*)d_in[0];
    const float* v     = (const float*)d_in[1];
    const float* gamma = (const float*)d_in[2];
    const float* beta  = (const float*)d_in[3];
    const float* U_W   = (const float*)d_in[4];
    const float* V_W   = (const float*)d_in[5];
    const float* W1    = (const float*)d_in[6];
    const float* b1    = (const float*)d_in[7];
    const float* W2    = (const float*)d_in[8];
    const float* b2    = (const float*)d_in[9];
    float* s_out = (float*)d_out;
    float* v_out = s_out + (size_t)NATOMS * H;
    unsigned short* P = (unsigned short*)d_ws;   // needs 917504 B

    pack_weights<<<dim3(224), dim3(256), 0, stream>>>(U_W, V_W, W1, W2, P);
    painn_main<<<dim3(NBLK), dim3(512), 0, stream>>>(s, v, gamma, beta, b1, b2, P, s_out, v_out);
}

// Round 13
// 431.303 us; speedup vs baseline: 1.8651x; 1.8651x over previous
//
#include <hip/hip_runtime.h>
#include <stdint.h>

#define H 256
#define NATOMS 100000
#define MB 32
#define NBLK (NATOMS / MB)   // 3125

typedef float floatx4 __attribute__((ext_vector_type(4)));
typedef short short8 __attribute__((ext_vector_type(8)));
typedef short short4v __attribute__((ext_vector_type(4)));

// lgkm-only barrier: global prefetches/stores stay in flight across it.
#define BAR() do { asm volatile("s_waitcnt lgkmcnt(0)\n\ts_barrier" ::: "memory"); __builtin_amdgcn_sched_barrier(0); } while (0)

__device__ __forceinline__ unsigned short f2bf(float x) {
    union { float f; uint32_t u; } c; c.f = x;
    return (unsigned short)((c.u + 0x7FFFu + ((c.u >> 16) & 1u)) >> 16);
}
__device__ __forceinline__ float bf2f(unsigned short h) {
    union { uint32_t u; float f; } c; c.u = ((uint32_t)h) << 16; return c.f;
}
__device__ __forceinline__ uint32_t pk2(float lo, float hi) {
    return (uint32_t)f2bf(lo) | ((uint32_t)f2bf(hi) << 16);
}
__device__ __forceinline__ float upk(uint32_t u, int hi) {
    union { uint32_t u; float f; } c;
    c.u = hi ? (u & 0xFFFF0000u) : (u << 16);
    return c.f;
}

// ---------------------------------------------------------------------------
// Pack weights (f32 [K][N] row-major) into bf16 MFMA-B-fragment order.
// frag fl = nb*(K/32)+kb; lane l holds W[kb*32+(l>>4)*8+e][nb*16+(l&15)].
// ws layout (bf16 elems): U@0, V@65536, W1@131072, W2@262144 (896KB total).
// ---------------------------------------------------------------------------
__global__ void pack_weights(const float* __restrict__ U_W, const float* __restrict__ V_W,
                             const float* __restrict__ W1, const float* __restrict__ W2,
                             unsigned short* __restrict__ P) {
    int gtid = blockIdx.x * 256 + threadIdx.x;
    int fid = gtid >> 6, l = gtid & 63;
    const float* src; int K, N, fl; unsigned short* dst;
    if (fid < 128)      { src = U_W; K = 256; N = 256; fl = fid;       dst = P; }
    else if (fid < 256) { src = V_W; K = 256; N = 256; fl = fid - 128; dst = P + 65536; }
    else if (fid < 512) { src = W1;  K = 512; N = 256; fl = fid - 256; dst = P + 131072; }
    else                { src = W2;  K = 256; N = 768; fl = fid - 512; dst = P + 262144; }
    int kbc = K >> 5;
    int nb = fl / kbc, kb = fl - nb * kbc;
    int k0 = kb * 32 + ((l >> 4) << 3);
    int n0 = nb * 16 + (l & 15);
    short8 outv;
#pragma unroll
    for (int e = 0; e < 8; e++) outv[e] = (short)f2bf(src[(size_t)(k0 + e) * N + n0]);
    *(short8*)(dst + (size_t)fl * 512 + l * 8) = outv;
}

// ---------------------------------------------------------------------------
// Fused PaiNN mixing (R8 structure + pass-boundary B chaining + early v_out).
// Block = 32 atoms, 512 thr (8 waves), LDS 64KB -> 2 blocks/CU (two
// independent barrier domains). Wave w owns cols [32w,32w+32) (cf 0..1).
// A-frags 1KB MFMA-linear w/ kpos-XOR swizzle;
// lane read off loff = (l>>4)*256 + ((l15^(l>>4))<<4).
// LDS map (one 64KB array):
//   [0,48K)  v-frags (g*24+d*8+ks)   [staging -> B2]
//   [0,16K)  slotX: Vv_norm frags (g*8+kn)  [B2 -> p2], then sdelta[a][c]
//   [16K,32K) slotY: hid frags (g*8+ks)     [p2 -> p3]
//   [48K,64K) LNf: s_norm frags (g*8+ks)    [stage -> p2]
// In regs: raw s (bf16 srp), Uv (bf16 uvh), dotv, a_vv. v re-read in epi,
// but v_out runs BEFORE B5 so its load latency hides under the barrier.
// ---------------------------------------------------------------------------
__global__ __launch_bounds__(512, 4) void painn_main(
    const float* __restrict__ s, const float* __restrict__ v,
    const float* __restrict__ gamma, const float* __restrict__ beta,
    const float* __restrict__ b1, const float* __restrict__ b2,
    const unsigned short* __restrict__ P,
    float* __restrict__ s_out, float* __restrict__ v_out) {

    __shared__ unsigned short SH[32768];   // 64KB
    char* LB = (char*)SH;

    const int tid = threadIdx.x;
    const int w = tid >> 6, l = tid & 63;
    const int l15 = l & 15, lhi = l >> 4;
    const int loff = (lhi << 8) | ((l15 ^ lhi) << 4);
    const int atom0 = blockIdx.x * MB;
    const int aLN = tid >> 4, lg = tid & 15;          // 16 lanes per atom
    const int gLN = aLN >> 4, a15LN = aLN & 15;

    // ---- stage v -> v-frags [0,48K) ----
    {
        const floatx4* vsrc = (const floatx4*)(v + (size_t)atom0 * 3 * H);
#pragma unroll
        for (int i = 0; i < 6; i++) {
            int p = i * 512 + tid;
            int a = p / 96, rem = p - a * 96;
            int d = rem >> 5, c8 = rem & 31;
            int q = ((a * 3 + d) << 6) + (c8 << 1);
            floatx4 x0 = vsrc[q], x1 = vsrc[q + 1];
            short8 pk;
#pragma unroll
            for (int j = 0; j < 4; j++) { pk[j] = (short)f2bf(x0[j]); pk[4 + j] = (short)f2bf(x1[j]); }
            int ks = c8 >> 2, kpos = c8 & 3;
            int bo = ((((a >> 4) * 24) + d * 8 + ks) << 10) + (kpos << 8) + (((a & 15) ^ kpos) << 4);
            *(short8*)(LB + bo) = pk;
        }
    }

    // ---- LayerNorm(s) -> LNf frags [48K,64K); raw s packed in regs ----
    short4v srp[4];
    {
        const floatx4* srow = (const floatx4*)(s + (size_t)(atom0 + aLN) * H);
        floatx4 vals[4];
        float sum = 0.f, sq = 0.f;
#pragma unroll
        for (int i = 0; i < 4; i++) {
            vals[i] = srow[lg + (i << 4)];
#pragma unroll
            for (int j = 0; j < 4; j++) { sum += vals[i][j]; sq += vals[i][j] * vals[i][j]; }
        }
#pragma unroll
        for (int m = 1; m < 16; m <<= 1) { sum += __shfl_xor(sum, m); sq += __shfl_xor(sq, m); }
        float mu = sum * (1.f / 256.f);
        float var = sq * (1.f / 256.f) - mu * mu;
        float rs = rsqrtf(var + 1e-5f);
#pragma unroll
        for (int i = 0; i < 4; i++) {
            int chunk = lg + (i << 4);
            floatx4 g4 = *(const floatx4*)(gamma + chunk * 4);
            floatx4 be4 = *(const floatx4*)(beta + chunk * 4);
            short4v pk, pr;
#pragma unroll
            for (int j = 0; j < 4; j++) {
                pk[j] = (short)f2bf((vals[i][j] - mu) * rs * g4[j] + be4[j]);
                pr[j] = (short)f2bf(vals[i][j]);
            }
            srp[i] = pr;
            int ks2 = chunk >> 3, kpos = (chunk >> 1) & 3, half = chunk & 1;
            int bo = 49152 + ((gLN * 8 + ks2) << 10) + (kpos << 8) + ((a15LN ^ kpos) << 4) + half * 8;
            *(short4v*)(LB + bo) = pk;
        }
    }

    // ---- p1 B prefetch (cf=0, slot0) before barrier ----
    const short8* PU = (const short8*)P;
    const short8* PV = (const short8*)(P + 65536);
    short8 bU[2], bV[2];
    bU[0] = PU[(size_t)((w * 2) * 8) * 64 + l];
    bV[0] = PV[(size_t)((w * 2) * 8) * 64 + l];

    BAR();  // B1: v-frags + LNf visible

    // ---- phase 1: Uv & Vv, per-cf passes (keeps VGPR low) ----
    float dotv[2][2][4];
    uint32_t uvh[2][3][2][2];   // [cf][d][g][pair] packed bf16
    uint32_t nvp[2][2][2];      // [cf][g][pair]   packed bf16
#pragma unroll
    for (int cf = 0; cf < 2; cf++) {
        int nb = w * 2 + cf;
        floatx4 accU[3][2], accV[3][2];
#pragma unroll
        for (int d = 0; d < 3; d++)
#pragma unroll
            for (int g = 0; g < 2; g++) { accU[d][g] = (floatx4)0.f; accV[d][g] = (floatx4)0.f; }
#pragma unroll
        for (int ks = 0; ks < 8; ks++) {
            int cur = ks & 1, nxt = cur ^ 1;
            if (ks < 7) {
                bU[nxt] = PU[(size_t)(nb * 8 + ks + 1) * 64 + l];
                bV[nxt] = PV[(size_t)(nb * 8 + ks + 1) * 64 + l];
            } else if (cf == 0) {
                // chain next pass's slot0: no pass-boundary bubble
                bU[nxt] = PU[(size_t)((nb + 1) * 8) * 64 + l];
                bV[nxt] = PV[(size_t)((nb + 1) * 8) * 64 + l];
            }
#pragma unroll
            for (int g = 0; g < 2; g++) {
                short8 af0 = *(const short8*)(LB + ((g * 24 + 0 * 8 + ks) << 10) + loff);
                short8 af1 = *(const short8*)(LB + ((g * 24 + 1 * 8 + ks) << 10) + loff);
                short8 af2 = *(const short8*)(LB + ((g * 24 + 2 * 8 + ks) << 10) + loff);
                __builtin_amdgcn_s_setprio(1);
                accU[0][g] = __builtin_amdgcn_mfma_f32_16x16x32_bf16(af0, bU[cur], accU[0][g], 0, 0, 0);
                accV[0][g] = __builtin_amdgcn_mfma_f32_16x16x32_bf16(af0, bV[cur], accV[0][g], 0, 0, 0);
                accU[1][g] = __builtin_amdgcn_mfma_f32_16x16x32_bf16(af1, bU[cur], accU[1][g], 0, 0, 0);
                accV[1][g] = __builtin_amdgcn_mfma_f32_16x16x32_bf16(af1, bV[cur], accV[1][g], 0, 0, 0);
                accU[2][g] = __builtin_amdgcn_mfma_f32_16x16x32_bf16(af2, bU[cur], accU[2][g], 0, 0, 0);
                accV[2][g] = __builtin_amdgcn_mfma_f32_16x16x32_bf16(af2, bV[cur], accV[2][g], 0, 0, 0);
                __builtin_amdgcn_s_setprio(0);
            }
        }
        // fold: dot_uv, ||Vv||, pack Uv -> bf16
#pragma unroll
        for (int g = 0; g < 2; g++) {
            float nv[4];
#pragma unroll
            for (int j = 0; j < 4; j++) {
                dotv[cf][g][j] = accU[0][g][j] * accV[0][g][j] + accU[1][g][j] * accV[1][g][j]
                               + accU[2][g][j] * accV[2][g][j];
                nv[j] = sqrtf(accV[0][g][j] * accV[0][g][j] + accV[1][g][j] * accV[1][g][j]
                            + accV[2][g][j] * accV[2][g][j] + 1e-8f);
            }
            nvp[cf][g][0] = pk2(nv[0], nv[1]);
            nvp[cf][g][1] = pk2(nv[2], nv[3]);
#pragma unroll
            for (int d = 0; d < 3; d++) {
                uvh[cf][d][g][0] = pk2(accU[d][g][0], accU[d][g][1]);
                uvh[cf][d][g][1] = pk2(accU[d][g][2], accU[d][g][3]);
            }
        }
    }

    BAR();  // B2: all v-frag reads done -> slotX/slotY writable

    // ---- Vv_norm -> slotX frags ----
#pragma unroll
    for (int cf = 0; cf < 2; cf++) {
        int kp = (cf << 1) | (l15 >> 3);
        int cb = (l15 & 7) << 1;
#pragma unroll
        for (int g = 0; g < 2; g++)
#pragma unroll
            for (int j = 0; j < 4; j++) {
                int a15 = (lhi << 2) + j;
                unsigned short hbits = (unsigned short)((j & 1) ? (nvp[cf][g][j >> 1] >> 16)
                                                                : (nvp[cf][g][j >> 1] & 0xFFFF));
                int bo = ((g * 8 + w) << 10) + (kp << 8) + ((a15 ^ kp) << 4) + cb;
                *(unsigned short*)(LB + bo) = hbits;
            }
    }

    // ---- p2 B prefetch ----
    const short8* PW1 = (const short8*)(P + 131072);
    short8 bw[2];
    bw[0] = PW1[(size_t)((w * 2) * 16) * 64 + l];

    BAR();  // B3: norm frags visible

    // ---- phase 2: hid = silu(ctx_in @ W1 + b1), per-cf passes ----
#pragma unroll
    for (int cf = 0; cf < 2; cf++) {
        int nb = w * 2 + cf;
        floatx4 acc2[2];
        acc2[0] = (floatx4)0.f; acc2[1] = (floatx4)0.f;
#pragma unroll
        for (int ks2 = 0; ks2 < 16; ks2++) {
            int cur = ks2 & 1, nxt = cur ^ 1;
            if (ks2 < 15) bw[nxt] = PW1[(size_t)(nb * 16 + ks2 + 1) * 64 + l];
            else if (cf == 0) bw[nxt] = PW1[(size_t)((nb + 1) * 16) * 64 + l];
            short8 af0 = (ks2 < 8)
                ? *(const short8*)(LB + 49152 + ((0 * 8 + ks2) << 10) + loff)
                : *(const short8*)(LB + ((0 * 8 + ks2 - 8) << 10) + loff);
            short8 af1 = (ks2 < 8)
                ? *(const short8*)(LB + 49152 + ((1 * 8 + ks2) << 10) + loff)
                : *(const short8*)(LB + ((1 * 8 + ks2 - 8) << 10) + loff);
            __builtin_amdgcn_s_setprio(1);
            acc2[0] = __builtin_amdgcn_mfma_f32_16x16x32_bf16(af0, bw[cur], acc2[0], 0, 0, 0);
            acc2[1] = __builtin_amdgcn_mfma_f32_16x16x32_bf16(af1, bw[cur], acc2[1], 0, 0, 0);
            __builtin_amdgcn_s_setprio(0);
        }
        // hid -> slotY frags (slotY free since B2; readers gated by B4)
        int c = (w << 5) + (cf << 4) + l15;
        float bb = b1[c];
        int kp = (cf << 1) | (l15 >> 3);
        int cb = (l15 & 7) << 1;
#pragma unroll
        for (int g = 0; g < 2; g++)
#pragma unroll
            for (int j = 0; j < 4; j++) {
                int a15 = (lhi << 2) + j;
                float x = acc2[g][j] + bb;
                float hh = x / (1.f + __expf(-x));
                int bo = 16384 + ((g * 8 + w) << 10) + (kp << 8) + ((a15 ^ kp) << 4) + cb;
                *(unsigned short*)(LB + bo) = f2bf(hh);
            }
    }

    // ---- p3 B prefetch (first pass = sv segment, sg=1) ----
    const short8* PW2 = (const short8*)(P + 262144);
    short8 b2w[2][2];
    b2w[0][0] = PW2[(size_t)((16 + w * 2 + 0) * 8) * 64 + l];
    b2w[0][1] = PW2[(size_t)((16 + w * 2 + 1) * 8) * 64 + l];

    BAR();  // B4: hid visible

    // ---- phase 3: per-segment passes sv -> ss -> vv (chained slot0s) ----
    float svd[2][2][4];   // sv*dot -> sdelta -> a_vv (reused)
    {   // sv (sg=1)
        floatx4 acc[2][2];
#pragma unroll
        for (int g = 0; g < 2; g++) { acc[g][0] = (floatx4)0.f; acc[g][1] = (floatx4)0.f; }
#pragma unroll
        for (int ks3 = 0; ks3 < 8; ks3++) {
            int cur = ks3 & 1, nxt = cur ^ 1;
            if (ks3 < 7) {
                b2w[nxt][0] = PW2[(size_t)((16 + w * 2 + 0) * 8 + ks3 + 1) * 64 + l];
                b2w[nxt][1] = PW2[(size_t)((16 + w * 2 + 1) * 8 + ks3 + 1) * 64 + l];
            } else {
                b2w[nxt][0] = PW2[(size_t)((0 + w * 2 + 0) * 8) * 64 + l];
                b2w[nxt][1] = PW2[(size_t)((0 + w * 2 + 1) * 8) * 64 + l];
            }
            short8 af0 = *(const short8*)(LB + 16384 + ((0 * 8 + ks3) << 10) + loff);
            short8 af1 = *(const short8*)(LB + 16384 + ((1 * 8 + ks3) << 10) + loff);
            __builtin_amdgcn_s_setprio(1);
            acc[0][0] = __builtin_amdgcn_mfma_f32_16x16x32_bf16(af0, b2w[cur][0], acc[0][0], 0, 0, 0);
            acc[0][1] = __builtin_amdgcn_mfma_f32_16x16x32_bf16(af0, b2w[cur][1], acc[0][1], 0, 0, 0);
            acc[1][0] = __builtin_amdgcn_mfma_f32_16x16x32_bf16(af1, b2w[cur][0], acc[1][0], 0, 0, 0);
            acc[1][1] = __builtin_amdgcn_mfma_f32_16x16x32_bf16(af1, b2w[cur][1], acc[1][1], 0, 0, 0);
            __builtin_amdgcn_s_setprio(0);
        }
#pragma unroll
        for (int cf = 0; cf < 2; cf++) {
            float bsv = b2[256 + (w << 5) + (cf << 4) + l15];
#pragma unroll
            for (int g = 0; g < 2; g++)
#pragma unroll
                for (int j = 0; j < 4; j++)
                    svd[cf][g][j] = (acc[g][cf][j] + bsv) * dotv[cf][g][j];
        }
    }
    {   // ss (sg=0)
        floatx4 acc[2][2];
#pragma unroll
        for (int g = 0; g < 2; g++) { acc[g][0] = (floatx4)0.f; acc[g][1] = (floatx4)0.f; }
#pragma unroll
        for (int ks3 = 0; ks3 < 8; ks3++) {
            int cur = ks3 & 1, nxt = cur ^ 1;
            if (ks3 < 7) {
                b2w[nxt][0] = PW2[(size_t)((w * 2 + 0) * 8 + ks3 + 1) * 64 + l];
                b2w[nxt][1] = PW2[(size_t)((w * 2 + 1) * 8 + ks3 + 1) * 64 + l];
            } else {
                b2w[nxt][0] = PW2[(size_t)((32 + w * 2 + 0) * 8) * 64 + l];
                b2w[nxt][1] = PW2[(size_t)((32 + w * 2 + 1) * 8) * 64 + l];
            }
            short8 af0 = *(const short8*)(LB + 16384 + ((0 * 8 + ks3) << 10) + loff);
            short8 af1 = *(const short8*)(LB + 16384 + ((1 * 8 + ks3) << 10) + loff);
            __builtin_amdgcn_s_setprio(1);
            acc[0][0] = __builtin_amdgcn_mfma_f32_16x16x32_bf16(af0, b2w[cur][0], acc[0][0], 0, 0, 0);
            acc[0][1] = __builtin_amdgcn_mfma_f32_16x16x32_bf16(af0, b2w[cur][1], acc[0][1], 0, 0, 0);
            acc[1][0] = __builtin_amdgcn_mfma_f32_16x16x32_bf16(af1, b2w[cur][0], acc[1][0], 0, 0, 0);
            acc[1][1] = __builtin_amdgcn_mfma_f32_16x16x32_bf16(af1, b2w[cur][1], acc[1][1], 0, 0, 0);
            __builtin_amdgcn_s_setprio(0);
        }
        // sdelta = (ss+bss) + sv*dot -> slotX [a][c] (norm frags dead since B4)
#pragma unroll
        for (int cf = 0; cf < 2; cf++) {
            int c = (w << 5) + (cf << 4) + l15;
            float bss = b2[c];
#pragma unroll
            for (int g = 0; g < 2; g++)
#pragma unroll
                for (int j = 0; j < 4; j++) {
                    int a = (g << 4) + (lhi << 2) + j;
                    float sd = (acc[g][cf][j] + bss) + svd[cf][g][j];
                    int bo = ((a << 9) + (c << 1)) ^ ((a & 7) << 4);
                    *(unsigned short*)(LB + bo) = f2bf(sd);
                }
        }
    }
    {   // vv (sg=2) -> a_vv kept in regs (svd reused)
        floatx4 acc[2][2];
#pragma unroll
        for (int g = 0; g < 2; g++) { acc[g][0] = (floatx4)0.f; acc[g][1] = (floatx4)0.f; }
#pragma unroll
        for (int ks3 = 0; ks3 < 8; ks3++) {
            int cur = ks3 & 1, nxt = cur ^ 1;
            if (ks3 < 7) {
                b2w[nxt][0] = PW2[(size_t)((32 + w * 2 + 0) * 8 + ks3 + 1) * 64 + l];
                b2w[nxt][1] = PW2[(size_t)((32 + w * 2 + 1) * 8 + ks3 + 1) * 64 + l];
            }
            short8 af0 = *(const short8*)(LB + 16384 + ((0 * 8 + ks3) << 10) + loff);
            short8 af1 = *(const short8*)(LB + 16384 + ((1 * 8 + ks3) << 10) + loff);
            __builtin_amdgcn_s_setprio(1);
            acc[0][0] = __builtin_amdgcn_mfma_f32_16x16x32_bf16(af0, b2w[cur][0], acc[0][0], 0, 0, 0);
            acc[0][1] = __builtin_amdgcn_mfma_f32_16x16x32_bf16(af0, b2w[cur][1], acc[0][1], 0, 0, 0);
            acc[1][0] = __builtin_amdgcn_mfma_f32_16x16x32_bf16(af1, b2w[cur][0], acc[1][0], 0, 0, 0);
            acc[1][1] = __builtin_amdgcn_mfma_f32_16x16x32_bf16(af1, b2w[cur][1], acc[1][1], 0, 0, 0);
            __builtin_amdgcn_s_setprio(0);
        }
#pragma unroll
        for (int cf = 0; cf < 2; cf++) {
            float bvv = b2[512 + (w << 5) + (cf << 4) + l15];
#pragma unroll
            for (int g = 0; g < 2; g++)
#pragma unroll
                for (int j = 0; j < 4; j++)
                    svd[cf][g][j] = acc[g][cf][j] + bvv;
        }
    }

    // ---- v_out epilogue BEFORE B5: independent of sdelta; its global-load
    //      latency hides under the barrier + other waves' p3/sdelta work ----
#pragma unroll
    for (int cf = 0; cf < 2; cf++) {
        int c = (w << 5) + (cf << 4) + l15;
#pragma unroll
        for (int g = 0; g < 2; g++)
#pragma unroll
            for (int j = 0; j < 4; j++) {
                int a = (g << 4) + (lhi << 2) + j;
                size_t base = (size_t)(atom0 + a) * 3 * H + c;
                float av = svd[cf][g][j];
#pragma unroll
                for (int d = 0; d < 3; d++) {
                    float uv = upk(uvh[cf][d][g][j >> 1], j & 1);
                    size_t vi = base + (size_t)d * H;
                    v_out[vi] = v[vi] + av * uv;
                }
            }
    }

    BAR();  // B5 (lgkm-only): sdelta visible; v_out stores stay in flight

    // ---- s_out epilogue (short tail): raw s from regs + sdelta from LDS ----
    {
        size_t gb = (size_t)(atom0 + aLN) * H;
        int xo = (aLN & 7) << 4;
#pragma unroll
        for (int i = 0; i < 4; i++) {
            int chunk = lg + (i << 4);
            short4v sd4 = *(const short4v*)(LB + (((aLN << 9) + (chunk << 3)) ^ xo));
            floatx4 o;
#pragma unroll
            for (int j = 0; j < 4; j++) o[j] = bf2f((unsigned short)srp[i][j]) + bf2f((unsigned short)sd4[j]);
            *(floatx4*)(s_out + gb + chunk * 4) = o;
        }
    }
}

extern "C" void kernel_launch(void* const* d_in, const int* in_sizes, int n_in,
                              void* d_out, int out_size, void* d_ws, size_t ws_size,
                              hipStream_t stream) {
    const float* s     = (const float*)d_in[0];
    const float* v     = (const float*)d_in[1];
    const float* gamma = (const float*)d_in[2];
    const float* beta  = (const float*)d_in[3];
    const float* U_W   = (const float*)d_in[4];
    const float* V_W   = (const float*)d_in[5];
    const float* W1    = (const float*)d_in[6];
    const float* b1    = (const float*)d_in[7];
    const float* W2    = (const float*)d_in[8];
    const float* b2    = (const float*)d_in[9];
    float* s_out = (float*)d_out;
    float* v_out = s_out + (size_t)NATOMS * H;
    unsigned short* P = (unsigned short*)d_ws;   // needs 917504 B

    pack_weights<<<dim3(224), dim3(256), 0, stream>>>(U_W, V_W, W1, W2, P);
    painn_main<<<dim3(NBLK), dim3(512), 0, stream>>>(s, v, gamma, beta, b1, b2, P, s_out, v_out);
}

// Round 14
// 394.700 us; speedup vs baseline: 2.0380x; 1.0927x over previous
//
#include <hip/hip_runtime.h>
#include <stdint.h>

#define H 256
#define NATOMS 100000
#define MB 32
#define NBLK (NATOMS / MB)   // 3125

typedef float floatx4 __attribute__((ext_vector_type(4)));
typedef short short8 __attribute__((ext_vector_type(8)));
typedef short short4v __attribute__((ext_vector_type(4)));

// lgkm-only barrier: global prefetches stay in flight across it.
#define BAR() do { asm volatile("s_waitcnt lgkmcnt(0)\n\ts_barrier" ::: "memory"); __builtin_amdgcn_sched_barrier(0); } while (0)

__device__ __forceinline__ unsigned short f2bf(float x) {
    union { float f; uint32_t u; } c; c.f = x;
    return (unsigned short)((c.u + 0x7FFFu + ((c.u >> 16) & 1u)) >> 16);
}
__device__ __forceinline__ float bf2f(unsigned short h) {
    union { uint32_t u; float f; } c; c.u = ((uint32_t)h) << 16; return c.f;
}
__device__ __forceinline__ uint32_t pk2(float lo, float hi) {
    return (uint32_t)f2bf(lo) | ((uint32_t)f2bf(hi) << 16);
}
__device__ __forceinline__ float upk(uint32_t u, int hi) {
    union { uint32_t u; float f; } c;
    c.u = hi ? (u & 0xFFFF0000u) : (u << 16);
    return c.f;
}

// ---------------------------------------------------------------------------
// Pack weights (f32 [K][N] row-major) into bf16 MFMA-B-fragment order.
// frag fl = nb*(K/32)+kb; lane l holds W[kb*32+(l>>4)*8+e][nb*16+(l&15)].
// ws layout (bf16 elems): U@0, V@65536, W1@131072, W2@262144 (896KB total).
// ---------------------------------------------------------------------------
__global__ void pack_weights(const float* __restrict__ U_W, const float* __restrict__ V_W,
                             const float* __restrict__ W1, const float* __restrict__ W2,
                             unsigned short* __restrict__ P) {
    int gtid = blockIdx.x * 256 + threadIdx.x;
    int fid = gtid >> 6, l = gtid & 63;
    const float* src; int K, N, fl; unsigned short* dst;
    if (fid < 128)      { src = U_W; K = 256; N = 256; fl = fid;       dst = P; }
    else if (fid < 256) { src = V_W; K = 256; N = 256; fl = fid - 128; dst = P + 65536; }
    else if (fid < 512) { src = W1;  K = 512; N = 256; fl = fid - 256; dst = P + 131072; }
    else                { src = W2;  K = 256; N = 768; fl = fid - 512; dst = P + 262144; }
    int kbc = K >> 5;
    int nb = fl / kbc, kb = fl - nb * kbc;
    int k0 = kb * 32 + ((l >> 4) << 3);
    int n0 = nb * 16 + (l & 15);
    short8 outv;
#pragma unroll
    for (int e = 0; e < 8; e++) outv[e] = (short)f2bf(src[(size_t)(k0 + e) * N + n0]);
    *(short8*)(dst + (size_t)fl * 512 + l * 8) = outv;
}

// ---------------------------------------------------------------------------
// Fused PaiNN mixing. Block = 32 atoms, 512 thr (8 waves), LDS 64KB ->
// 2 blocks/CU (two independent barrier domains). Wave w owns cols
// [32w,32w+32) (cf 0..1). A-frags 1KB MFMA-linear w/ kpos-XOR swizzle;
// lane read off loff = (l>>4)*256 + ((l15^(l>>4))<<4).
// LDS map (one 64KB array):
//   [0,48K)  v-frags (g*24+d*8+ks)   [staging -> end of p1]
//   [0,16K)  slotX: Vv_norm frags (g*8+kn)  [B2 -> p2], then sdelta[a][c] [p3 -> epi]
//   [16K,32K) slotY: hid frags (g*8+ks)     [p2 -> p3]
//   [48K,64K) LNf: s_norm frags (g*8+ks)    [stage -> p2]
// In regs: raw s (bf16, srp), Uv (bf16 packed, uvh), dot_uv, a_vv.
// Per-cf p1 / per-seg p3 passes keep VGPR <= 128 (4 waves/SIMD).
// Tail v_out (v re-read, L2-warm) overlaps the next block's prologue.
// ---------------------------------------------------------------------------
__global__ __launch_bounds__(512, 4) void painn_main(
    const float* __restrict__ s, const float* __restrict__ v,
    const float* __restrict__ gamma, const float* __restrict__ beta,
    const float* __restrict__ b1, const float* __restrict__ b2,
    const unsigned short* __restrict__ P,
    float* __restrict__ s_out, float* __restrict__ v_out) {

    __shared__ unsigned short SH[32768];   // 64KB
    char* LB = (char*)SH;

    const int tid = threadIdx.x;
    const int w = tid >> 6, l = tid & 63;
    const int l15 = l & 15, lhi = l >> 4;
    const int loff = (lhi << 8) | ((l15 ^ lhi) << 4);
    const int atom0 = blockIdx.x * MB;
    const int aLN = tid >> 4, lg = tid & 15;          // 16 lanes per atom
    const int gLN = aLN >> 4, a15LN = aLN & 15;

    // ---- stage v -> v-frags [0,48K) ----
    {
        const floatx4* vsrc = (const floatx4*)(v + (size_t)atom0 * 3 * H);
#pragma unroll
        for (int i = 0; i < 6; i++) {
            int p = i * 512 + tid;
            int a = p / 96, rem = p - a * 96;
            int d = rem >> 5, c8 = rem & 31;
            int q = ((a * 3 + d) << 6) + (c8 << 1);
            floatx4 x0 = vsrc[q], x1 = vsrc[q + 1];
            short8 pk;
#pragma unroll
            for (int j = 0; j < 4; j++) { pk[j] = (short)f2bf(x0[j]); pk[4 + j] = (short)f2bf(x1[j]); }
            int ks = c8 >> 2, kpos = c8 & 3;
            int bo = ((((a >> 4) * 24) + d * 8 + ks) << 10) + (kpos << 8) + (((a & 15) ^ kpos) << 4);
            *(short8*)(LB + bo) = pk;
        }
    }

    // ---- LayerNorm(s) -> LNf frags [48K,64K); raw s packed in regs ----
    short4v srp[4];
    {
        const floatx4* srow = (const floatx4*)(s + (size_t)(atom0 + aLN) * H);
        floatx4 vals[4];
        float sum = 0.f, sq = 0.f;
#pragma unroll
        for (int i = 0; i < 4; i++) {
            vals[i] = srow[lg + (i << 4)];
#pragma unroll
            for (int j = 0; j < 4; j++) { sum += vals[i][j]; sq += vals[i][j] * vals[i][j]; }
        }
#pragma unroll
        for (int m = 1; m < 16; m <<= 1) { sum += __shfl_xor(sum, m); sq += __shfl_xor(sq, m); }
        float mu = sum * (1.f / 256.f);
        float var = sq * (1.f / 256.f) - mu * mu;
        float rs = rsqrtf(var + 1e-5f);
#pragma unroll
        for (int i = 0; i < 4; i++) {
            int chunk = lg + (i << 4);
            floatx4 g4 = *(const floatx4*)(gamma + chunk * 4);
            floatx4 be4 = *(const floatx4*)(beta + chunk * 4);
            short4v pk, pr;
#pragma unroll
            for (int j = 0; j < 4; j++) {
                pk[j] = (short)f2bf((vals[i][j] - mu) * rs * g4[j] + be4[j]);
                pr[j] = (short)f2bf(vals[i][j]);
            }
            srp[i] = pr;
            int ks2 = chunk >> 3, kpos = (chunk >> 1) & 3, half = chunk & 1;
            int bo = 49152 + ((gLN * 8 + ks2) << 10) + (kpos << 8) + ((a15LN ^ kpos) << 4) + half * 8;
            *(short4v*)(LB + bo) = pk;
        }
    }

    // ---- p1 B prefetch (cf=0, slot0) before barrier ----
    const short8* PU = (const short8*)P;
    const short8* PV = (const short8*)(P + 65536);
    short8 bU[2], bV[2];
    bU[0] = PU[(size_t)((w * 2) * 8) * 64 + l];
    bV[0] = PV[(size_t)((w * 2) * 8) * 64 + l];

    BAR();  // B1: v-frags + LNf visible

    // ---- phase 1: Uv & Vv, per-cf passes (keeps VGPR low) ----
    float dotv[2][2][4];
    uint32_t uvh[2][3][2][2];   // [cf][d][g][pair] packed bf16
    uint32_t nvp[2][2][2];      // [cf][g][pair]   packed bf16
#pragma unroll
    for (int cf = 0; cf < 2; cf++) {
        int nb = w * 2 + cf;
        if (cf == 1) {
            bU[0] = PU[(size_t)(nb * 8) * 64 + l];
            bV[0] = PV[(size_t)(nb * 8) * 64 + l];
        }
        floatx4 accU[3][2], accV[3][2];
#pragma unroll
        for (int d = 0; d < 3; d++)
#pragma unroll
            for (int g = 0; g < 2; g++) { accU[d][g] = (floatx4)0.f; accV[d][g] = (floatx4)0.f; }
#pragma unroll
        for (int ks = 0; ks < 8; ks++) {
            int cur = ks & 1, nxt = cur ^ 1;
            if (ks < 7) {
                bU[nxt] = PU[(size_t)(nb * 8 + ks + 1) * 64 + l];
                bV[nxt] = PV[(size_t)(nb * 8 + ks + 1) * 64 + l];
            }
#pragma unroll
            for (int g = 0; g < 2; g++) {
                short8 af0 = *(const short8*)(LB + ((g * 24 + 0 * 8 + ks) << 10) + loff);
                short8 af1 = *(const short8*)(LB + ((g * 24 + 1 * 8 + ks) << 10) + loff);
                short8 af2 = *(const short8*)(LB + ((g * 24 + 2 * 8 + ks) << 10) + loff);
                __builtin_amdgcn_s_setprio(1);
                accU[0][g] = __builtin_amdgcn_mfma_f32_16x16x32_bf16(af0, bU[cur], accU[0][g], 0, 0, 0);
                accV[0][g] = __builtin_amdgcn_mfma_f32_16x16x32_bf16(af0, bV[cur], accV[0][g], 0, 0, 0);
                accU[1][g] = __builtin_amdgcn_mfma_f32_16x16x32_bf16(af1, bU[cur], accU[1][g], 0, 0, 0);
                accV[1][g] = __builtin_amdgcn_mfma_f32_16x16x32_bf16(af1, bV[cur], accV[1][g], 0, 0, 0);
                accU[2][g] = __builtin_amdgcn_mfma_f32_16x16x32_bf16(af2, bU[cur], accU[2][g], 0, 0, 0);
                accV[2][g] = __builtin_amdgcn_mfma_f32_16x16x32_bf16(af2, bV[cur], accV[2][g], 0, 0, 0);
                __builtin_amdgcn_s_setprio(0);
            }
        }
        // fold: dot_uv, ||Vv||, pack Uv -> bf16
#pragma unroll
        for (int g = 0; g < 2; g++) {
            float nv[4];
#pragma unroll
            for (int j = 0; j < 4; j++) {
                dotv[cf][g][j] = accU[0][g][j] * accV[0][g][j] + accU[1][g][j] * accV[1][g][j]
                               + accU[2][g][j] * accV[2][g][j];
                nv[j] = sqrtf(accV[0][g][j] * accV[0][g][j] + accV[1][g][j] * accV[1][g][j]
                            + accV[2][g][j] * accV[2][g][j] + 1e-8f);
            }
            nvp[cf][g][0] = pk2(nv[0], nv[1]);
            nvp[cf][g][1] = pk2(nv[2], nv[3]);
#pragma unroll
            for (int d = 0; d < 3; d++) {
                uvh[cf][d][g][0] = pk2(accU[d][g][0], accU[d][g][1]);
                uvh[cf][d][g][1] = pk2(accU[d][g][2], accU[d][g][3]);
            }
        }
    }

    BAR();  // B2: all v-frag reads done -> slotX/slotY writable

    // ---- Vv_norm -> slotX frags ----
#pragma unroll
    for (int cf = 0; cf < 2; cf++) {
        int kp = (cf << 1) | (l15 >> 3);
        int cb = (l15 & 7) << 1;
#pragma unroll
        for (int g = 0; g < 2; g++)
#pragma unroll
            for (int j = 0; j < 4; j++) {
                int a15 = (lhi << 2) + j;
                unsigned short hbits = (unsigned short)((j & 1) ? (nvp[cf][g][j >> 1] >> 16)
                                                                : (nvp[cf][g][j >> 1] & 0xFFFF));
                int bo = ((g * 8 + w) << 10) + (kp << 8) + ((a15 ^ kp) << 4) + cb;
                *(unsigned short*)(LB + bo) = hbits;
            }
    }

    // ---- p2 B prefetch ----
    const short8* PW1 = (const short8*)(P + 131072);
    short8 bw[2];
    bw[0] = PW1[(size_t)((w * 2) * 16) * 64 + l];

    BAR();  // B3: norm frags visible

    // ---- phase 2: hid = silu(ctx_in @ W1 + b1), per-cf passes ----
#pragma unroll
    for (int cf = 0; cf < 2; cf++) {
        int nb = w * 2 + cf;
        if (cf == 1) bw[0] = PW1[(size_t)(nb * 16) * 64 + l];
        floatx4 acc2[2];
        acc2[0] = (floatx4)0.f; acc2[1] = (floatx4)0.f;
#pragma unroll
        for (int ks2 = 0; ks2 < 16; ks2++) {
            int cur = ks2 & 1, nxt = cur ^ 1;
            if (ks2 < 15) bw[nxt] = PW1[(size_t)(nb * 16 + ks2 + 1) * 64 + l];
            short8 af0 = (ks2 < 8)
                ? *(const short8*)(LB + 49152 + ((0 * 8 + ks2) << 10) + loff)
                : *(const short8*)(LB + ((0 * 8 + ks2 - 8) << 10) + loff);
            short8 af1 = (ks2 < 8)
                ? *(const short8*)(LB + 49152 + ((1 * 8 + ks2) << 10) + loff)
                : *(const short8*)(LB + ((1 * 8 + ks2 - 8) << 10) + loff);
            __builtin_amdgcn_s_setprio(1);
            acc2[0] = __builtin_amdgcn_mfma_f32_16x16x32_bf16(af0, bw[cur], acc2[0], 0, 0, 0);
            acc2[1] = __builtin_amdgcn_mfma_f32_16x16x32_bf16(af1, bw[cur], acc2[1], 0, 0, 0);
            __builtin_amdgcn_s_setprio(0);
        }
        // hid -> slotY frags (slotY free since B2; readers gated by B4)
        int c = (w << 5) + (cf << 4) + l15;
        float bb = b1[c];
        int kp = (cf << 1) | (l15 >> 3);
        int cb = (l15 & 7) << 1;
#pragma unroll
        for (int g = 0; g < 2; g++)
#pragma unroll
            for (int j = 0; j < 4; j++) {
                int a15 = (lhi << 2) + j;
                float x = acc2[g][j] + bb;
                float hh = x / (1.f + __expf(-x));
                int bo = 16384 + ((g * 8 + w) << 10) + (kp << 8) + ((a15 ^ kp) << 4) + cb;
                *(unsigned short*)(LB + bo) = f2bf(hh);
            }
    }

    // ---- p3 B prefetch (first pass = sv segment, sg=1) ----
    const short8* PW2 = (const short8*)(P + 262144);
    short8 b2w[2][2];
    b2w[0][0] = PW2[(size_t)((16 + w * 2 + 0) * 8) * 64 + l];
    b2w[0][1] = PW2[(size_t)((16 + w * 2 + 1) * 8) * 64 + l];

    BAR();  // B4: hid visible

    // ---- phase 3: per-segment passes sv -> ss -> vv ----
    float svd[2][2][4];   // sv*dot -> sdelta -> a_vv (reused)
    {   // sv (sg=1)
        floatx4 acc[2][2];
#pragma unroll
        for (int g = 0; g < 2; g++) { acc[g][0] = (floatx4)0.f; acc[g][1] = (floatx4)0.f; }
#pragma unroll
        for (int ks3 = 0; ks3 < 8; ks3++) {
            int cur = ks3 & 1, nxt = cur ^ 1;
            if (ks3 < 7) {
                b2w[nxt][0] = PW2[(size_t)((16 + w * 2 + 0) * 8 + ks3 + 1) * 64 + l];
                b2w[nxt][1] = PW2[(size_t)((16 + w * 2 + 1) * 8 + ks3 + 1) * 64 + l];
            }
            short8 af0 = *(const short8*)(LB + 16384 + ((0 * 8 + ks3) << 10) + loff);
            short8 af1 = *(const short8*)(LB + 16384 + ((1 * 8 + ks3) << 10) + loff);
            __builtin_amdgcn_s_setprio(1);
            acc[0][0] = __builtin_amdgcn_mfma_f32_16x16x32_bf16(af0, b2w[cur][0], acc[0][0], 0, 0, 0);
            acc[0][1] = __builtin_amdgcn_mfma_f32_16x16x32_bf16(af0, b2w[cur][1], acc[0][1], 0, 0, 0);
            acc[1][0] = __builtin_amdgcn_mfma_f32_16x16x32_bf16(af1, b2w[cur][0], acc[1][0], 0, 0, 0);
            acc[1][1] = __builtin_amdgcn_mfma_f32_16x16x32_bf16(af1, b2w[cur][1], acc[1][1], 0, 0, 0);
            __builtin_amdgcn_s_setprio(0);
        }
#pragma unroll
        for (int cf = 0; cf < 2; cf++) {
            float bsv = b2[256 + (w << 5) + (cf << 4) + l15];
#pragma unroll
            for (int g = 0; g < 2; g++)
#pragma unroll
                for (int j = 0; j < 4; j++)
                    svd[cf][g][j] = (acc[g][cf][j] + bsv) * dotv[cf][g][j];
        }
    }
    {   // ss (sg=0)
        b2w[0][0] = PW2[(size_t)((0 + w * 2 + 0) * 8) * 64 + l];
        b2w[0][1] = PW2[(size_t)((0 + w * 2 + 1) * 8) * 64 + l];
        floatx4 acc[2][2];
#pragma unroll
        for (int g = 0; g < 2; g++) { acc[g][0] = (floatx4)0.f; acc[g][1] = (floatx4)0.f; }
#pragma unroll
        for (int ks3 = 0; ks3 < 8; ks3++) {
            int cur = ks3 & 1, nxt = cur ^ 1;
            if (ks3 < 7) {
                b2w[nxt][0] = PW2[(size_t)((w * 2 + 0) * 8 + ks3 + 1) * 64 + l];
                b2w[nxt][1] = PW2[(size_t)((w * 2 + 1) * 8 + ks3 + 1) * 64 + l];
            }
            short8 af0 = *(const short8*)(LB + 16384 + ((0 * 8 + ks3) << 10) + loff);
            short8 af1 = *(const short8*)(LB + 16384 + ((1 * 8 + ks3) << 10) + loff);
            __builtin_amdgcn_s_setprio(1);
            acc[0][0] = __builtin_amdgcn_mfma_f32_16x16x32_bf16(af0, b2w[cur][0], acc[0][0], 0, 0, 0);
            acc[0][1] = __builtin_amdgcn_mfma_f32_16x16x32_bf16(af0, b2w[cur][1], acc[0][1], 0, 0, 0);
            acc[1][0] = __builtin_amdgcn_mfma_f32_16x16x32_bf16(af1, b2w[cur][0], acc[1][0], 0, 0, 0);
            acc[1][1] = __builtin_amdgcn_mfma_f32_16x16x32_bf16(af1, b2w[cur][1], acc[1][1], 0, 0, 0);
            __builtin_amdgcn_s_setprio(0);
        }
        // sdelta = (ss+bss) + sv*dot -> slotX [a][c] (norm frags dead since B4)
#pragma unroll
        for (int cf = 0; cf < 2; cf++) {
            int c = (w << 5) + (cf << 4) + l15;
            float bss = b2[c];
#pragma unroll
            for (int g = 0; g < 2; g++)
#pragma unroll
                for (int j = 0; j < 4; j++) {
                    int a = (g << 4) + (lhi << 2) + j;
                    float sd = (acc[g][cf][j] + bss) + svd[cf][g][j];
                    int bo = ((a << 9) + (c << 1)) ^ ((a & 7) << 4);
                    *(unsigned short*)(LB + bo) = f2bf(sd);
                }
        }
    }
    {   // vv (sg=2) -> a_vv kept in regs (svd reused)
        b2w[0][0] = PW2[(size_t)((32 + w * 2 + 0) * 8) * 64 + l];
        b2w[0][1] = PW2[(size_t)((32 + w * 2 + 1) * 8) * 64 + l];
        floatx4 acc[2][2];
#pragma unroll
        for (int g = 0; g < 2; g++) { acc[g][0] = (floatx4)0.f; acc[g][1] = (floatx4)0.f; }
#pragma unroll
        for (int ks3 = 0; ks3 < 8; ks3++) {
            int cur = ks3 & 1, nxt = cur ^ 1;
            if (ks3 < 7) {
                b2w[nxt][0] = PW2[(size_t)((32 + w * 2 + 0) * 8 + ks3 + 1) * 64 + l];
                b2w[nxt][1] = PW2[(size_t)((32 + w * 2 + 1) * 8 + ks3 + 1) * 64 + l];
            }
            short8 af0 = *(const short8*)(LB + 16384 + ((0 * 8 + ks3) << 10) + loff);
            short8 af1 = *(const short8*)(LB + 16384 + ((1 * 8 + ks3) << 10) + loff);
            __builtin_amdgcn_s_setprio(1);
            acc[0][0] = __builtin_amdgcn_mfma_f32_16x16x32_bf16(af0, b2w[cur][0], acc[0][0], 0, 0, 0);
            acc[0][1] = __builtin_amdgcn_mfma_f32_16x16x32_bf16(af0, b2w[cur][1], acc[0][1], 0, 0, 0);
            acc[1][0] = __builtin_amdgcn_mfma_f32_16x16x32_bf16(af1, b2w[cur][0], acc[1][0], 0, 0, 0);
            acc[1][1] = __builtin_amdgcn_mfma_f32_16x16x32_bf16(af1, b2w[cur][1], acc[1][1], 0, 0, 0);
            __builtin_amdgcn_s_setprio(0);
        }
#pragma unroll
        for (int cf = 0; cf < 2; cf++) {
            float bvv = b2[512 + (w << 5) + (cf << 4) + l15];
#pragma unroll
            for (int g = 0; g < 2; g++)
#pragma unroll
                for (int j = 0; j < 4; j++)
                    svd[cf][g][j] = acc[g][cf][j] + bvv;
        }
    }

    BAR();  // B5: sdelta visible

    // ---- epilogue: s_out (LN map; raw s from regs; 256B contiguous) ----
    {
        size_t gb = (size_t)(atom0 + aLN) * H;
        int xo = (aLN & 7) << 4;
#pragma unroll
        for (int i = 0; i < 4; i++) {
            int chunk = lg + (i << 4);
            short4v sd4 = *(const short4v*)(LB + (((aLN << 9) + (chunk << 3)) ^ xo));
            floatx4 o;
#pragma unroll
            for (int j = 0; j < 4; j++) o[j] = bf2f((unsigned short)srp[i][j]) + bf2f((unsigned short)sd4[j]);
            *(floatx4*)(s_out + gb + chunk * 4) = o;
        }
    }

    // ---- epilogue: v_out = v + a_vv * Uv (acc map; v re-read, L2-warm).
    //      Tail stall overlaps the next block's staging prologue on this CU.
#pragma unroll
    for (int cf = 0; cf < 2; cf++) {
        int c = (w << 5) + (cf << 4) + l15;
#pragma unroll
        for (int g = 0; g < 2; g++)
#pragma unroll
            for (int j = 0; j < 4; j++) {
                int a = (g << 4) + (lhi << 2) + j;
                size_t base = (size_t)(atom0 + a) * 3 * H + c;
                float av = svd[cf][g][j];
#pragma unroll
                for (int d = 0; d < 3; d++) {
                    float uv = upk(uvh[cf][d][g][j >> 1], j & 1);
                    size_t vi = base + (size_t)d * H;
                    v_out[vi] = v[vi] + av * uv;
                }
            }
    }
}

extern "C" void kernel_launch(void* const* d_in, const int* in_sizes, int n_in,
                              void* d_out, int out_size, void* d_ws, size_t ws_size,
                              hipStream_t stream) {
    const float* s     = (const float*)d_in[0];
    const float* v     = (const float*)d_in[1];
    const float* gamma = (const float*)d_in[2];
    const float* beta  = (const float*)d_in[3];
    const float* U_W   = (const float*)d_in[4];
    const float* V_W   = (const float*)d_in[5];
    const float* W1    = (const float*)d_in[6];
    const float* b1    = (const float*)d_in[7];
    const float* W2    = (const float*)d_in[8];
    const float* b2    = (const float*)d_in[9];
    float* s_out = (float*)d_out;
    float* v_out = s_out + (size_t)NATOMS * H;
    unsigned short* P = (unsigned short*)d_ws;   // needs 917504 B

    pack_weights<<<dim3(224), dim3(256), 0, stream>>>(U_W, V_W, W1, W2, P);
    painn_main<<<dim3(NBLK), dim3(512), 0, stream>>>(s, v, gamma, beta, b1, b2, P, s_out, v_out);
}